// Round 8
// baseline (436.959 us; speedup 1.0000x reference)
//
#include <hip/hip_runtime.h>
#include <hip/hip_bf16.h>
#include <math.h>

#define NROWS 1048576
#define D 256
#define C 65
#define MT 4                 // cluster tiles of 16 -> c 0..63 via MFMA; c=64 via VALU
#define KS 8                 // k-steps of 32 (K=256)
#define TILES_PER_WAVE 8
#define TILES_PER_BLOCK 32   // 4 waves * 8 -> 512 rows/block, grid 2048

typedef float f32x4  __attribute__((ext_vector_type(4)));
typedef short bf16x8 __attribute__((ext_vector_type(8)));

__device__ __forceinline__ short f2bf(float f) {
    __hip_bfloat16 h = __float2bfloat16(f);   // RNE hw cvt
    return *reinterpret_cast<short*>(&h);
}

// --- Pre-kernel: weight norms -> d_ws (65 floats). One wave per cluster. ---
__global__ void wn_kernel(const float* __restrict__ w, float* __restrict__ wn) {
    int c = blockIdx.x;
    int l = threadIdx.x;
    float s = 0.f;
    #pragma unroll
    for (int d = l; d < D; d += 64) {
        float v = w[c * D + d];
        s = fmaf(v, v, s);
    }
    #pragma unroll
    for (int off = 32; off; off >>= 1) s += __shfl_down(s, off);
    if (l == 0) wn[c] = sqrtf(s);
}

// --- Main kernel: bf16 MFMA (c<64) + VALU dot (c=64); FULL-TILE distance-1
// prefetch (16KB/wave in flight across MFMA+epilogue); LDS-restaged stores.
// LDS caps occupancy at 3 blocks/CU -> declare 3 waves/SIMD so VGPR budget=168.
__global__ __launch_bounds__(256, 3) void scluster_mfma(
    const float* __restrict__ x, const float* __restrict__ w,
    const float* __restrict__ wn, float* __restrict__ out)
{
    __shared__ bf16x8 wfrag[MT * KS * 64];   // 32KB prepacked, prenormalized A-frags
    __shared__ float  wb64[D];               // 1KB: w_hat[64][*] in f32
    __shared__ float  obuf[4][16 * C];       // 16.6KB per-wave store staging

    const int tid = threadIdx.x;

    // ---- stage A-fragments: f=(m,ks,lane): w_hat[m*16+(lane&15)][ks*32+(lane>>4)*8+j]
    #pragma unroll 1
    for (int f = tid; f < MT * KS * 64; f += 256) {
        const int m  = f >> 9;
        const int ks = (f >> 6) & 7;
        const int l  = f & 63;
        const int c    = m * 16 + (l & 15);
        const int koff = ks * 32 + (l >> 4) * 8;
        const float inv = __builtin_amdgcn_rcpf(wn[c]);
        const f32x4 a = *reinterpret_cast<const f32x4*>(&w[c * D + koff]);
        const f32x4 b = *reinterpret_cast<const f32x4*>(&w[c * D + koff + 4]);
        bf16x8 fr;
        fr[0] = f2bf(a.x * inv); fr[1] = f2bf(a.y * inv);
        fr[2] = f2bf(a.z * inv); fr[3] = f2bf(a.w * inv);
        fr[4] = f2bf(b.x * inv); fr[5] = f2bf(b.y * inv);
        fr[6] = f2bf(b.z * inv); fr[7] = f2bf(b.w * inv);
        wfrag[f] = fr;
    }
    if (tid < 64) {
        const float inv = __builtin_amdgcn_rcpf(wn[64]);
        const f32x4 a = *reinterpret_cast<const f32x4*>(&w[64 * D + tid * 4]);
        f32x4 v; v.x = a.x * inv; v.y = a.y * inv; v.z = a.z * inv; v.w = a.w * inv;
        *reinterpret_cast<f32x4*>(&wb64[tid * 4]) = v;
    }
    __syncthreads();

    const int wv   = tid >> 6;
    const int l    = tid & 63;
    const int g    = l >> 4;     // k-group within fragment
    const int jrow = l & 15;     // this lane's x-row; owned end-to-end

    const int   tile0 = blockIdx.x * TILES_PER_BLOCK + wv * TILES_PER_WAVE;
    const size_t row0 = (size_t)tile0 * 16 + jrow;
    const float* __restrict__ xp0 = x + row0 * D + g * 8;
    float* const tb = obuf[wv];

    f32x4 p[16];                 // full-tile load buffer (64 VGPR, 16KB/wave in flight)
    #pragma unroll
    for (int k = 0; k < 8; ++k) {
        p[2 * k]     = *reinterpret_cast<const f32x4*>(xp0 + k * 32);
        p[2 * k + 1] = *reinterpret_cast<const f32x4*>(xp0 + k * 32 + 4);
    }

    #pragma unroll 1
    for (int it = 0; it < TILES_PER_WAVE; ++it) {
        const float* __restrict__ xq = xp0 + (size_t)(it + 1) * 16 * D;  // next tile

        f32x4 acc[MT];
        #pragma unroll
        for (int m = 0; m < MT; ++m) acc[m] = f32x4{0.f, 0.f, 0.f, 0.f};
        float xn2 = 0.f, acc64 = 0.f;

        bf16x8 xf[8];

        // ---- consume whole tile (progressive vmcnt drain): cvt + xn2 + c64
        #pragma unroll
        for (int k = 0; k < 8; ++k) {
            const f32x4 a = p[2 * k], b = p[2 * k + 1];
            xn2 = fmaf(a.x, a.x, xn2); xn2 = fmaf(a.y, a.y, xn2);
            xn2 = fmaf(a.z, a.z, xn2); xn2 = fmaf(a.w, a.w, xn2);
            xn2 = fmaf(b.x, b.x, xn2); xn2 = fmaf(b.y, b.y, xn2);
            xn2 = fmaf(b.z, b.z, xn2); xn2 = fmaf(b.w, b.w, xn2);
            const f32x4 wa = *reinterpret_cast<const f32x4*>(&wb64[g * 8 + k * 32]);
            const f32x4 wb = *reinterpret_cast<const f32x4*>(&wb64[g * 8 + k * 32 + 4]);
            acc64 = fmaf(wa.x, a.x, acc64); acc64 = fmaf(wa.y, a.y, acc64);
            acc64 = fmaf(wa.z, a.z, acc64); acc64 = fmaf(wa.w, a.w, acc64);
            acc64 = fmaf(wb.x, b.x, acc64); acc64 = fmaf(wb.y, b.y, acc64);
            acc64 = fmaf(wb.z, b.z, acc64); acc64 = fmaf(wb.w, b.w, acc64);
            bf16x8 f;
            f[0] = f2bf(a.x); f[1] = f2bf(a.y); f[2] = f2bf(a.z); f[3] = f2bf(a.w);
            f[4] = f2bf(b.x); f[5] = f2bf(b.y); f[6] = f2bf(b.z); f[7] = f2bf(b.w);
            xf[k] = f;
        }
        // ---- p[] now free: issue ENTIRE next tile (in flight across MFMA+epilogue)
        if (it < TILES_PER_WAVE - 1) {
            #pragma unroll
            for (int k = 0; k < 8; ++k) {
                p[2 * k]     = *reinterpret_cast<const f32x4*>(xq + k * 32);
                p[2 * k + 1] = *reinterpret_cast<const f32x4*>(xq + k * 32 + 4);
            }
        }
        __builtin_amdgcn_sched_barrier(0);   // loads stay above the MFMA phase
        // ---- MFMA: all 8 k-steps
        #pragma unroll
        for (int ks = 0; ks < KS; ++ks)
            #pragma unroll
            for (int m = 0; m < MT; ++m)
                acc[m] = __builtin_amdgcn_mfma_f32_16x16x32_bf16(
                    wfrag[(m * KS + ks) * 64 + l], xf[ks], acc[m], 0, 0, 0);

        // ---- epilogue: reduces, softmax, LDS restage, full-line stores
        xn2   += __shfl_xor(xn2, 16);   xn2   += __shfl_xor(xn2, 32);
        acc64 += __shfl_xor(acc64, 16); acc64 += __shfl_xor(acc64, 32);
        const float rxn = __builtin_amdgcn_rcpf(sqrtf(xn2));
        const float s64 = acc64 * rxn;

        float mx = s64;
        #pragma unroll
        for (int m = 0; m < MT; ++m) {
            #pragma unroll
            for (int r = 0; r < 4; ++r) {
                const float v = acc[m][r] * rxn;
                acc[m][r] = v;
                mx = fmaxf(mx, v);
            }
        }
        mx = fmaxf(mx, __shfl_xor(mx, 16));
        mx = fmaxf(mx, __shfl_xor(mx, 32));

        const float e64 = __expf(s64 - mx);
        float sum = (g == 0) ? e64 : 0.f;
        #pragma unroll
        for (int m = 0; m < MT; ++m) {
            #pragma unroll
            for (int r = 0; r < 4; ++r) {
                const float e = __expf(acc[m][r] - mx);
                acc[m][r] = e;
                sum += e;
            }
        }
        sum += __shfl_xor(sum, 16);
        sum += __shfl_xor(sum, 32);
        const float rs = __builtin_amdgcn_rcpf(sum);

        // scatter this wave's 16x65 tile into LDS (banks (jrow+c)%32, <=4-way)
        #pragma unroll
        for (int m = 0; m < MT; ++m) {
            #pragma unroll
            for (int r = 0; r < 4; ++r)
                tb[jrow * C + m * 16 + g * 4 + r] = acc[m][r] * rs;
        }
        if (g == 0) tb[jrow * C + 64] = e64 * rs;
        asm volatile("s_waitcnt lgkmcnt(0)" ::: "memory");  // same-wave ds order

        // 16*65 floats = 4160B = 65 full lines; aligned f32x4 coalesced NT stores
        const size_t gb = (size_t)(tile0 + it) * 16 * C;
        #pragma unroll
        for (int rd = 0; rd < 4; ++rd) {
            const int idx = rd * 64 + l;
            const f32x4 v = *reinterpret_cast<const f32x4*>(&tb[idx * 4]);
            __builtin_nontemporal_store(v, reinterpret_cast<f32x4*>(&out[gb + idx * 4]));
        }
        if (l < 4) {
            const int idx = 256 + l;
            const f32x4 v = *reinterpret_cast<const f32x4*>(&tb[idx * 4]);
            __builtin_nontemporal_store(v, reinterpret_cast<f32x4*>(&out[gb + idx * 4]));
        }
    }
}

extern "C" void kernel_launch(void* const* d_in, const int* in_sizes, int n_in,
                              void* d_out, int out_size, void* d_ws, size_t ws_size,
                              hipStream_t stream) {
    const float* x = (const float*)d_in[0];
    const float* w = (const float*)d_in[1];
    float* out = (float*)d_out;
    float* wn = (float*)d_ws;

    wn_kernel<<<C, 64, 0, stream>>>(w, wn);
    scluster_mfma<<<NROWS / 16 / TILES_PER_BLOCK, 256, 0, stream>>>(x, w, wn, out);
}